// Round 1
// baseline (1034.346 us; speedup 1.0000x reference)
//
#include <hip/hip_runtime.h>
#include <hip/hip_bf16.h>

typedef __bf16 bf16x8_t __attribute__((ext_vector_type(8)));
typedef float f32x4_t __attribute__((ext_vector_type(4)));

#define B_ROWS 16
#define NSTEPS 100

// LDS map (64 KB static):
//  [0, 32768)      : sbuf  - spike / hidden A-fragment buffer (16x1024 bf16, MFMA-A layout)
//                    later: pooled CNN fragments 16x1600 bf16 = [0, 51200)
//                    later: P4 partials [0, 16384)
//  [32768, 49152)  : pbuf0 (partial C tiles, fp32)
//  [49152, 65536)  : pbuf1
//  [53248, 65536)  : comb-input fragments (12 k-chunks), live only after SNN flush
#define PBUF0 32768u
#define PBUF1 49152u
#define COMBF 53248u

__device__ __forceinline__ unsigned short f2bfu(float v) {
  union { __bf16 h; unsigned short u; } c;
  c.h = (__bf16)v;   // RTNE hardware convert
  return c.u;
}
__device__ __forceinline__ unsigned int pack2bf(float a, float b) {
  return (unsigned int)f2bfu(a) | ((unsigned int)f2bfu(b) << 16);
}

union BF8U {
  unsigned int u[4];
  bf16x8_t v;
};

// 8 consecutive fp32 -> bf16x8 fragment (optionally scaled)
__device__ __forceinline__ bf16x8_t load_bfrag_f32(const float* __restrict__ p, float scale) {
  BF8U r;
#pragma unroll
  for (int i = 0; i < 4; ++i) r.u[i] = pack2bf(p[2*i] * scale, p[2*i+1] * scale);
  return r.v;
}

// store one bf16 value into the comb-input fragment region at position (k, row m)
__device__ __forceinline__ void comb_store(unsigned char* ldsp, int k, int mm, float v) {
  *(unsigned short*)(ldsp + COMBF + (unsigned)((k >> 5) * 1024 + (((k >> 3) & 3) * 16 + mm) * 16 + (k & 7) * 2)) = f2bfu(v);
}

__global__ __launch_bounds__(512, 2)
void hybrid_fused(const float* __restrict__ x,
                  const float* __restrict__ snn_w1, const float* __restrict__ snn_b1,
                  const float* __restrict__ snn_w2, const float* __restrict__ snn_b2,
                  const float* __restrict__ nn_w1,  const float* __restrict__ nn_b1,
                  const float* __restrict__ nn_w2,  const float* __restrict__ nn_b2,
                  const float* __restrict__ conv_w, const float* __restrict__ conv_b,
                  const float* __restrict__ fc_w,   const float* __restrict__ fc_b,
                  const float* __restrict__ comb_w, const float* __restrict__ comb_b,
                  float* __restrict__ out)
{
  __shared__ __align__(16) unsigned char lds[65536];
  const int tid  = threadIdx.x;
  const int row0 = blockIdx.x * B_ROWS;

  // layer-2 LIF state: lives in MFMA-wave registers (lane holds 4 (m,n) cells of C)
  float m2[4]  = {0.f, 0.f, 0.f, 0.f};
  float s2[4]  = {0.f, 0.f, 0.f, 0.f};
  float cnt[4] = {0.f, 0.f, 0.f, 0.f};

  if (tid < 256) {
    //=================== neuron role: waves 0..3 ===================
    const int m  = tid & 15;        // batch row within tile
    const int cb = tid >> 4;        // 0..15 -> neurons [cb*64, cb*64+64)
    float c[64];
    float mem[64];
    unsigned int pk[32];

    {
      const float* xr = x + (row0 + m) * 105;
      const float f0 = xr[0], f1 = xr[1], f2 = xr[2], f3 = xr[3], f4 = xr[4];
#pragma unroll
      for (int i = 0; i < 64; ++i) {
        const int k = cb * 64 + i;
        const float* w = snn_w1 + k * 5;
        c[i]  = f0*w[0] + f1*w[1] + f2*w[2] + f3*w[3] + f4*w[4] + snn_b1[k];
        mem[i] = 0.f;
      }
    }
    // update #1 -> spikes(t=0).  spk_prev derived from mem (invariant: spk == mem>1)
#pragma unroll
    for (int i = 0; i < 64; i += 2) {
      const float sp0 = mem[i]   > 1.f ? 1.f : 0.f;
      const float sp1 = mem[i+1] > 1.f ? 1.f : 0.f;
      mem[i]   = __fsub_rn(__fadd_rn(__fmul_rn(0.95f, mem[i]),   c[i]),   sp0);
      mem[i+1] = __fsub_rn(__fadd_rn(__fmul_rn(0.95f, mem[i+1]), c[i+1]), sp1);
      pk[i>>1] = (mem[i] > 1.f ? 0x3F80u : 0u) | (mem[i+1] > 1.f ? 0x3F800000u : 0u);
    }
#pragma unroll
    for (int g = 0; g < 8; ++g) {
      const int kc   = cb*2 + (g >> 2);
      const int lane = (g & 3)*16 + m;
      *(uint4*)(lds + (unsigned)(kc*1024 + lane*16)) =
          make_uint4(pk[4*g], pk[4*g+1], pk[4*g+2], pk[4*g+3]);
    }
    __syncthreads();   // #1: spikes(0) visible

#pragma unroll 1
    for (int t = 0; t < NSTEPS; ++t) {
      if (t < NSTEPS - 1) {
#pragma unroll
        for (int i = 0; i < 64; i += 2) {
          const float sp0 = mem[i]   > 1.f ? 1.f : 0.f;
          const float sp1 = mem[i+1] > 1.f ? 1.f : 0.f;
          mem[i]   = __fsub_rn(__fadd_rn(__fmul_rn(0.95f, mem[i]),   c[i]),   sp0);
          mem[i+1] = __fsub_rn(__fadd_rn(__fmul_rn(0.95f, mem[i+1]), c[i+1]), sp1);
          pk[i>>1] = (mem[i] > 1.f ? 0x3F80u : 0u) | (mem[i+1] > 1.f ? 0x3F800000u : 0u);
        }
      }
      __syncthreads();   // W1 end: MFMA waves done reading sbuf(t)
      if (t < NSTEPS - 1) {
#pragma unroll
        for (int g = 0; g < 8; ++g) {
          const int kc   = cb*2 + (g >> 2);
          const int lane = (g & 3)*16 + m;
          *(uint4*)(lds + (unsigned)(kc*1024 + lane*16)) =
              make_uint4(pk[4*g], pk[4*g+1], pk[4*g+2], pk[4*g+3]);
        }
      }
      __syncthreads();   // W2 end: spikes(t+1) visible
    }

    // ---- NN hidden: h = relu(feats @ nn_w1.T + nn_b1) -> bf16 fragments in sbuf ----
    {
      const float* xr = x + (row0 + m) * 105;
      const float f0 = xr[0], f1 = xr[1], f2 = xr[2], f3 = xr[3], f4 = xr[4];
      unsigned int hk[32];
#pragma unroll
      for (int i = 0; i < 64; i += 2) {
        const int k = cb * 64 + i;
        const float* wa = nn_w1 + k * 5;
        const float* wb = nn_w1 + (k + 1) * 5;
        float h0 = f0*wa[0] + f1*wa[1] + f2*wa[2] + f3*wa[3] + f4*wa[4] + nn_b1[k];
        float h1 = f0*wb[0] + f1*wb[1] + f2*wb[2] + f3*wb[3] + f4*wb[4] + nn_b1[k+1];
        h0 = fmaxf(h0, 0.f); h1 = fmaxf(h1, 0.f);
        hk[i>>1] = pack2bf(h0, h1);
      }
#pragma unroll
      for (int g = 0; g < 8; ++g) {
        const int kc   = cb*2 + (g >> 2);
        const int lane = (g & 3)*16 + m;
        *(uint4*)(lds + (unsigned)(kc*1024 + lane*16)) =
            make_uint4(hk[4*g], hk[4*g+1], hk[4*g+2], hk[4*g+3]);
      }
    }
  } else {
    //=================== MFMA role: waves 4..7 ===================
    const int l  = tid & 63;
    const int wm = (tid >> 6) - 4;    // 0..3 : K-quarter
    const float b2l = snn_b2[wm*16 + (l & 15)];
    bf16x8_t bfr[8][4];               // resident snn_w2 B-fragments: 8 k-chunks x 4 n-tiles
#pragma unroll
    for (int kci = 0; kci < 8; ++kci)
#pragma unroll
      for (int nt = 0; nt < 4; ++nt) {
        const int n  = nt*16 + (l & 15);
        const int kb = (wm*8 + kci)*32 + (l >> 4)*8;
        bfr[kci][nt] = load_bfrag_f32(snn_w2 + n*1024 + kb, 1.f);
      }
    __syncthreads();   // #1

#pragma unroll 1
    for (int t = 0; t < NSTEPS; ++t) {
      f32x4_t acc0 = {0.f,0.f,0.f,0.f};
      f32x4_t acc1 = {0.f,0.f,0.f,0.f};
      f32x4_t acc2 = {0.f,0.f,0.f,0.f};
      f32x4_t acc3 = {0.f,0.f,0.f,0.f};
#pragma unroll
      for (int kci = 0; kci < 8; ++kci) {
        const bf16x8_t a = *(const bf16x8_t*)(lds + (unsigned)(((wm*8 + kci)*64 + l)*16));
        acc0 = __builtin_amdgcn_mfma_f32_16x16x32_bf16(a, bfr[kci][0], acc0, 0, 0, 0);
        acc1 = __builtin_amdgcn_mfma_f32_16x16x32_bf16(a, bfr[kci][1], acc1, 0, 0, 0);
        acc2 = __builtin_amdgcn_mfma_f32_16x16x32_bf16(a, bfr[kci][2], acc2, 0, 0, 0);
        acc3 = __builtin_amdgcn_mfma_f32_16x16x32_bf16(a, bfr[kci][3], acc3, 0, 0, 0);
      }
      if (t > 0) {   // reduce step t-1 partials, update layer-2 LIF (1-step delayed)
        const unsigned pb = ((t - 1) & 1) ? PBUF1 : PBUF0;
        const f32x4_t p0 = *(const f32x4_t*)(lds + pb + (unsigned)(((0*4 + wm)*64 + l)*16));
        const f32x4_t p1 = *(const f32x4_t*)(lds + pb + (unsigned)(((1*4 + wm)*64 + l)*16));
        const f32x4_t p2 = *(const f32x4_t*)(lds + pb + (unsigned)(((2*4 + wm)*64 + l)*16));
        const f32x4_t p3 = *(const f32x4_t*)(lds + pb + (unsigned)(((3*4 + wm)*64 + l)*16));
#pragma unroll
        for (int r = 0; r < 4; ++r) {
          const float cur = ((p0[r] + p1[r]) + (p2[r] + p3[r])) + b2l;
          m2[r] = __fsub_rn(__fadd_rn(__fmul_rn(0.95f, m2[r]), cur), s2[r]);
          s2[r] = m2[r] > 1.f ? 1.f : 0.f;
          cnt[r] += s2[r];
        }
      }
      __syncthreads();
      const unsigned pw = (t & 1) ? PBUF1 : PBUF0;
      *(f32x4_t*)(lds + pw + (unsigned)(((wm*4 + 0)*64 + l)*16)) = acc0;
      *(f32x4_t*)(lds + pw + (unsigned)(((wm*4 + 1)*64 + l)*16)) = acc1;
      *(f32x4_t*)(lds + pw + (unsigned)(((wm*4 + 2)*64 + l)*16)) = acc2;
      *(f32x4_t*)(lds + pw + (unsigned)(((wm*4 + 3)*64 + l)*16)) = acc3;
      __syncthreads();
    }
    // flush: reduce t=99 partials (in pbuf1)
    {
      const f32x4_t p0 = *(const f32x4_t*)(lds + PBUF1 + (unsigned)(((0*4 + wm)*64 + l)*16));
      const f32x4_t p1 = *(const f32x4_t*)(lds + PBUF1 + (unsigned)(((1*4 + wm)*64 + l)*16));
      const f32x4_t p2 = *(const f32x4_t*)(lds + PBUF1 + (unsigned)(((2*4 + wm)*64 + l)*16));
      const f32x4_t p3 = *(const f32x4_t*)(lds + PBUF1 + (unsigned)(((3*4 + wm)*64 + l)*16));
#pragma unroll
      for (int r = 0; r < 4; ++r) {
        const float cur = ((p0[r] + p1[r]) + (p2[r] + p3[r])) + b2l;
        m2[r] = __fsub_rn(__fadd_rn(__fmul_rn(0.95f, m2[r]), cur), s2[r]);
        s2[r] = m2[r] > 1.f ? 1.f : 0.f;
        cnt[r] += s2[r];
      }
    }
  }

  __syncthreads();   // B1: hidden fragments visible
  // ---- NN matmul: hidden(16x1024) @ nn_w2.T -> partials ----
  if (tid >= 256) {
    const int l  = tid & 63;
    const int wm = (tid >> 6) - 4;
    f32x4_t aa[4];
#pragma unroll
    for (int nt = 0; nt < 4; ++nt) { f32x4_t z = {0.f,0.f,0.f,0.f}; aa[nt] = z; }
#pragma unroll
    for (int kci = 0; kci < 8; ++kci) {
      const bf16x8_t a = *(const bf16x8_t*)(lds + (unsigned)(((wm*8 + kci)*64 + l)*16));
      const int kb = (wm*8 + kci)*32 + (l >> 4)*8;
#pragma unroll
      for (int nt = 0; nt < 4; ++nt) {
        const int n = nt*16 + (l & 15);
        const bf16x8_t b = load_bfrag_f32(nn_w2 + n*1024 + kb, 1.f);
        aa[nt] = __builtin_amdgcn_mfma_f32_16x16x32_bf16(a, b, aa[nt], 0, 0, 0);
      }
    }
#pragma unroll
    for (int nt = 0; nt < 4; ++nt)
      *(f32x4_t*)(lds + PBUF0 + (unsigned)(((wm*4 + nt)*64 + l)*16)) = aa[nt];
  }
  __syncthreads();   // B2
  // ---- NN reduce -> comb[64..127]; SNN counts -> comb[0..63] (exact cnt/128) ----
  if (tid >= 256) {
    const int l  = tid & 63;
    const int wm = (tid >> 6) - 4;
    const f32x4_t p0 = *(const f32x4_t*)(lds + PBUF0 + (unsigned)(((0*4 + wm)*64 + l)*16));
    const f32x4_t p1 = *(const f32x4_t*)(lds + PBUF0 + (unsigned)(((1*4 + wm)*64 + l)*16));
    const f32x4_t p2 = *(const f32x4_t*)(lds + PBUF0 + (unsigned)(((2*4 + wm)*64 + l)*16));
    const f32x4_t p3 = *(const f32x4_t*)(lds + PBUF0 + (unsigned)(((3*4 + wm)*64 + l)*16));
    const int n = wm*16 + (l & 15);
    const float bnn = nn_b2[n];
#pragma unroll
    for (int r = 0; r < 4; ++r) {
      const int mm = (l >> 4)*4 + r;
      comb_store(lds, 64 + n, mm, ((p0[r] + p1[r]) + (p2[r] + p3[r])) + bnn);
      comb_store(lds, n, mm, cnt[r] * 0.0078125f);
    }
  }
  __syncthreads();   // B3 (pbuf0/sbuf now reusable)
  // ---- CNN conv + relu + pairwise maxpool -> pooled bf16 fragments at [0, 51200) ----
  {
    const int mm = tid & 15;
    const int ch = tid >> 4;          // 0..31
    const float cw0 = conv_w[ch*3+0], cw1 = conv_w[ch*3+1], cw2 = conv_w[ch*3+2];
    const float cbb = conv_b[ch];
    const float* xr = x + (row0 + mm)*105 + 5;
    float xm1 = 0.f;
    float x0  = xr[0];
#pragma unroll 1
    for (int q = 0; q < 50; ++q) {
      const float xp1 = xr[2*q + 1];
      const float xp2 = (q < 49) ? xr[2*q + 2] : 0.f;
      float a0 = cw0*xm1 + cw1*x0  + cw2*xp1 + cbb;
      float a1 = cw0*x0  + cw1*xp1 + cw2*xp2 + cbb;
      a0 = fmaxf(a0, 0.f); a1 = fmaxf(a1, 0.f);
      const float pv = fmaxf(a0, a1);
      const int k = ch*50 + q;
      *(unsigned short*)(lds + (unsigned)((k >> 5)*1024 + (((k >> 3) & 3)*16 + mm)*16 + (k & 7)*2)) = f2bfu(pv);
      xm1 = xp1; x0 = xp2;
    }
  }
  __syncthreads();   // B4: pooled visible
  // ---- CNN fc: pooled(16x1600) @ fc_w.T -> comb[128..383] (full K per wave, n-split) ----
  if (tid >= 256) {
    const int l  = tid & 63;
    const int wm = (tid >> 6) - 4;    // n-slice: [wm*64, wm*64+64)
    f32x4_t aa[4];
#pragma unroll
    for (int nt = 0; nt < 4; ++nt) { f32x4_t z = {0.f,0.f,0.f,0.f}; aa[nt] = z; }
#pragma unroll 1
    for (int kc = 0; kc < 50; ++kc) {
      const bf16x8_t a = *(const bf16x8_t*)(lds + (unsigned)((kc*64 + l)*16));
      const int kb = kc*32 + (l >> 4)*8;
#pragma unroll
      for (int nt = 0; nt < 4; ++nt) {
        const int n = wm*64 + nt*16 + (l & 15);
        const bf16x8_t b = load_bfrag_f32(fc_w + n*1600 + kb, 1.f);
        aa[nt] = __builtin_amdgcn_mfma_f32_16x16x32_bf16(a, b, aa[nt], 0, 0, 0);
      }
    }
#pragma unroll
    for (int nt = 0; nt < 4; ++nt) {
      const int n = wm*64 + nt*16 + (l & 15);
      const float bias = fc_b[n];
#pragma unroll
      for (int r = 0; r < 4; ++r)
        comb_store(lds, 128 + n, (l >> 4)*4 + r, aa[nt][r] + bias);
    }
  }
  __syncthreads();   // B5: comb-input fragments complete
  // ---- comb matmul: combined(16x384) @ comb_w.T (K split over 4 waves, 3 kc each) ----
  if (tid >= 256) {
    const int l  = tid & 63;
    const int wm = (tid >> 6) - 4;
    f32x4_t oc[4];
#pragma unroll
    for (int nt = 0; nt < 4; ++nt) { f32x4_t z = {0.f,0.f,0.f,0.f}; oc[nt] = z; }
#pragma unroll
    for (int kci = 0; kci < 3; ++kci) {
      const int kc = wm*3 + kci;
      const bf16x8_t a = *(const bf16x8_t*)(lds + COMBF + (unsigned)((kc*64 + l)*16));
      const float scale = (kc < 2) ? 1.28f : 1.f;   // undo the /128 on snn counts -> /100
      const int kb = kc*32 + (l >> 4)*8;
#pragma unroll
      for (int nt = 0; nt < 4; ++nt) {
        const int n = nt*16 + (l & 15);
        const bf16x8_t b = load_bfrag_f32(comb_w + n*384 + kb, scale);
        oc[nt] = __builtin_amdgcn_mfma_f32_16x16x32_bf16(a, b, oc[nt], 0, 0, 0);
      }
    }
#pragma unroll
    for (int nt = 0; nt < 4; ++nt)
      *(f32x4_t*)(lds + (unsigned)(((wm*4 + nt)*64 + l)*16)) = oc[nt];   // partials at base 0
  }
  __syncthreads();   // B6
  if (tid >= 256) {
    const int l  = tid & 63;
    const int wm = (tid >> 6) - 4;
    const f32x4_t q0 = *(const f32x4_t*)(lds + (unsigned)(((0*4 + wm)*64 + l)*16));
    const f32x4_t q1 = *(const f32x4_t*)(lds + (unsigned)(((1*4 + wm)*64 + l)*16));
    const f32x4_t q2 = *(const f32x4_t*)(lds + (unsigned)(((2*4 + wm)*64 + l)*16));
    const f32x4_t q3 = *(const f32x4_t*)(lds + (unsigned)(((3*4 + wm)*64 + l)*16));
    const int n = wm*16 + (l & 15);
    const float cbias = comb_b[n];
#pragma unroll
    for (int r = 0; r < 4; ++r) {
      const int mm = (l >> 4)*4 + r;
      out[(row0 + mm)*64 + n] = ((q0[r] + q1[r]) + (q2[r] + q3[r])) + cbias;
    }
  }
}

extern "C" void kernel_launch(void* const* d_in, const int* in_sizes, int n_in,
                              void* d_out, int out_size, void* d_ws, size_t ws_size,
                              hipStream_t stream) {
  const float* x       = (const float*)d_in[0];
  const float* snn_w1  = (const float*)d_in[1];
  const float* snn_b1  = (const float*)d_in[2];
  const float* snn_w2  = (const float*)d_in[3];
  const float* snn_b2  = (const float*)d_in[4];
  const float* nn_w1   = (const float*)d_in[5];
  const float* nn_b1   = (const float*)d_in[6];
  const float* nn_w2   = (const float*)d_in[7];
  const float* nn_b2   = (const float*)d_in[8];
  const float* conv_w  = (const float*)d_in[9];
  const float* conv_b  = (const float*)d_in[10];
  const float* fc_w    = (const float*)d_in[11];
  const float* fc_b    = (const float*)d_in[12];
  const float* comb_w  = (const float*)d_in[13];
  const float* comb_b  = (const float*)d_in[14];
  float* outp = (float*)d_out;

  const int rows = in_sizes[0] / 105;          // 16384
  const int grid = rows / B_ROWS;              // 1024

  hybrid_fused<<<dim3(grid), dim3(512), 0, stream>>>(
      x, snn_w1, snn_b1, snn_w2, snn_b2,
      nn_w1, nn_b1, nn_w2, nn_b2,
      conv_w, conv_b, fc_w, fc_b, comb_w, comb_b, outp);
}

// Round 2
// 925.619 us; speedup vs baseline: 1.1175x; 1.1175x over previous
//
#include <hip/hip_runtime.h>

typedef __bf16 bf16x8_t __attribute__((ext_vector_type(8)));
typedef float f32x4_t __attribute__((ext_vector_type(4)));

#define NSTEPS 100
#define COMBF 51200u   // comb-input bf16 fragments live at [51200, 63488)

static __device__ __forceinline__ unsigned short f2bfu(float v) {
  union { __bf16 h; unsigned short u; } c; c.h = (__bf16)v; return c.u;  // RTNE
}
static __device__ __forceinline__ unsigned int pack2bf(float a, float b) {
  return (unsigned)f2bfu(a) | ((unsigned)f2bfu(b) << 16);
}
union BF8U { unsigned int u[4]; bf16x8_t v; };

static __device__ __forceinline__ bf16x8_t bfrag_f32(const float* __restrict__ p, float s) {
  BF8U r;
#pragma unroll
  for (int i = 0; i < 4; ++i) r.u[i] = pack2bf(p[2*i]*s, p[2*i+1]*s);
  return r.v;
}

// store one bf16 element into an A-fragment-layout buffer at byte base CB
static __device__ __forceinline__ void comb_store(unsigned char* ldsp, int k, int row, float v) {
  *(unsigned short*)(ldsp + COMBF +
      (unsigned)((k >> 5)*1024 + (((k >> 3) & 3)*16 + row)*16 + (k & 7)*2)) = f2bfu(v);
}

__global__ __launch_bounds__(1024) __attribute__((amdgpu_waves_per_eu(4, 4)))
void hybrid_v2(const float* __restrict__ x,
               const float* __restrict__ snn_w1, const float* __restrict__ snn_b1,
               const float* __restrict__ snn_w2, const float* __restrict__ snn_b2,
               const float* __restrict__ nn_w1,  const float* __restrict__ nn_b1,
               const float* __restrict__ nn_w2,  const float* __restrict__ nn_b2,
               const float* __restrict__ conv_w, const float* __restrict__ conv_b,
               const float* __restrict__ fc_w,   const float* __restrict__ fc_b,
               const float* __restrict__ comb_w, const float* __restrict__ comb_b,
               const unsigned short* __restrict__ fcwb, int use_bf,
               float* __restrict__ out)
{
  __shared__ __align__(16) unsigned char lds[65536];   // partial buffer / pooled / comb frags
  const int tid  = threadIdx.x;
  const int w    = tid >> 6;        // wave 0..15: owns K-chunks {2w, 2w+1}
  const int l    = tid & 63;
  const int row0 = blockIdx.x * 16;

  const int m  = l & 15;            // A-row of this lane's fragment cells
  const int q  = l >> 4;            // quad (k sub-offset q*8)
  // reduction-cell mapping: lane owns output cell (rn, rm)
  const int rnt = w & 3;
  const int rq  = w >> 2;
  const int rn  = rnt*16 + m;       // 0..63
  const int rm  = rq*4 + q;         // 0..15

  // ---- per-lane inputs ----
  const float* xr = x + (row0 + m)*105;
  const float f0 = xr[0], f1 = xr[1], f2 = xr[2], f3 = xr[3], f4 = xr[4];
  const float b2l = snn_b2[rn];
  const float cbl = comb_b[rn];

  // ---- resident snn_w2 B-fragments: 2 chunks x 4 n-tiles (32 VGPRs) ----
  bf16x8_t bfr[2][4];
#pragma unroll
  for (int ci = 0; ci < 2; ++ci)
#pragma unroll
    for (int nt = 0; nt < 4; ++nt)
      bfr[ci][nt] = bfrag_f32(snn_w2 + (nt*16 + m)*1024 + (2*w + ci)*32 + q*8, 1.f);

  // ---- layer-1 LIF state: lane's own 16 A-fragment cells ----
  float c[16], mem[16];
#pragma unroll
  for (int ci = 0; ci < 2; ++ci)
#pragma unroll
    for (int j = 0; j < 8; ++j) {
      const int k = (2*w + ci)*32 + q*8 + j;
      const float* wr = snn_w1 + k*5;
      c[ci*8+j] = f0*wr[0] + f1*wr[1] + f2*wr[2] + f3*wr[3] + f4*wr[4] + snn_b1[k];
      mem[ci*8+j] = 0.f;
    }

  BF8U afr0, afr1;
  auto lif_update_pack = [&]() {
#pragma unroll
    for (int i = 0; i < 16; ++i) {
      const float sp = mem[i] > 1.f ? 1.f : 0.f;               // spk == (mem>1) invariant
      mem[i] = __fsub_rn(__fadd_rn(__fmul_rn(0.95f, mem[i]), c[i]), sp);  // exact np order
    }
#pragma unroll
    for (int jj = 0; jj < 4; ++jj) {
      afr0.u[jj] = (mem[2*jj]   > 1.f ? 0x3F80u : 0u) | (mem[2*jj+1]   > 1.f ? 0x3F800000u : 0u);
      afr1.u[jj] = (mem[8+2*jj] > 1.f ? 0x3F80u : 0u) | (mem[8+2*jj+1] > 1.f ? 0x3F800000u : 0u);
    }
  };
  lif_update_pack();                 // spikes(t=0) now in afr registers

  // ---- layer-2 LIF state: one scalar cell per lane ----
  float m2 = 0.f, s2 = 0.f, cnt = 0.f;

  const f32x4_t z4 = {0.f, 0.f, 0.f, 0.f};

#pragma unroll 1
  for (int t = 0; t < NSTEPS; ++t) {
    // PHASE A: MFMA on spikes(t); LIF(t+1) overlaps MFMA latency (independent)
    f32x4_t a0 = __builtin_amdgcn_mfma_f32_16x16x32_bf16(afr0.v, bfr[0][0], z4, 0,0,0);
    f32x4_t a1 = __builtin_amdgcn_mfma_f32_16x16x32_bf16(afr0.v, bfr[0][1], z4, 0,0,0);
    f32x4_t a2 = __builtin_amdgcn_mfma_f32_16x16x32_bf16(afr0.v, bfr[0][2], z4, 0,0,0);
    f32x4_t a3 = __builtin_amdgcn_mfma_f32_16x16x32_bf16(afr0.v, bfr[0][3], z4, 0,0,0);
    a0 = __builtin_amdgcn_mfma_f32_16x16x32_bf16(afr1.v, bfr[1][0], a0, 0,0,0);
    a1 = __builtin_amdgcn_mfma_f32_16x16x32_bf16(afr1.v, bfr[1][1], a1, 0,0,0);
    a2 = __builtin_amdgcn_mfma_f32_16x16x32_bf16(afr1.v, bfr[1][2], a2, 0,0,0);
    a3 = __builtin_amdgcn_mfma_f32_16x16x32_bf16(afr1.v, bfr[1][3], a3, 0,0,0);
    if (t < NSTEPS - 1) lif_update_pack();          // afr <- spikes(t+1)
    *(f32x4_t*)(lds + (unsigned)(((w*4 + 0)*64 + l)*16)) = a0;
    *(f32x4_t*)(lds + (unsigned)(((w*4 + 1)*64 + l)*16)) = a1;
    *(f32x4_t*)(lds + (unsigned)(((w*4 + 2)*64 + l)*16)) = a2;
    *(f32x4_t*)(lds + (unsigned)(((w*4 + 3)*64 + l)*16)) = a3;
    __syncthreads();
    // PHASE B: reduce 16 K-partials for this lane's cell, layer-2 LIF
    float v[16];
#pragma unroll
    for (int s = 0; s < 16; ++s)
      v[s] = *(const float*)(lds + (unsigned)(((s*4 + rnt)*64 + rq*16 + m)*16 + q*4));
    float cur = (((v[0]+v[1]) + (v[2]+v[3])) + ((v[4]+v[5]) + (v[6]+v[7])))
              + (((v[8]+v[9]) + (v[10]+v[11])) + ((v[12]+v[13]) + (v[14]+v[15])));
    cur += b2l;
    m2 = __fsub_rn(__fadd_rn(__fmul_rn(0.95f, m2), cur), s2);
    s2 = m2 > 1.f ? 1.f : 0.f;
    cnt += s2;
    __syncthreads();
  }

  // ================= NN branch (reuses the same machinery) =================
#pragma unroll
  for (int ci = 0; ci < 2; ++ci)
#pragma unroll
    for (int nt = 0; nt < 4; ++nt)
      bfr[ci][nt] = bfrag_f32(nn_w2 + (nt*16 + m)*1024 + (2*w + ci)*32 + q*8, 1.f);
  {
    BF8U h0, h1;
#pragma unroll
    for (int ci = 0; ci < 2; ++ci)
#pragma unroll
      for (int jj = 0; jj < 4; ++jj) {
        float hv[2];
#pragma unroll
        for (int e = 0; e < 2; ++e) {
          const int k = (2*w + ci)*32 + q*8 + 2*jj + e;
          const float* wr = nn_w1 + k*5;
          float h = f0*wr[0] + f1*wr[1] + f2*wr[2] + f3*wr[3] + f4*wr[4] + nn_b1[k];
          hv[e] = fmaxf(h, 0.f);
        }
        if (ci == 0) h0.u[jj] = pack2bf(hv[0], hv[1]);
        else         h1.u[jj] = pack2bf(hv[0], hv[1]);
      }
    f32x4_t a0 = __builtin_amdgcn_mfma_f32_16x16x32_bf16(h0.v, bfr[0][0], z4, 0,0,0);
    f32x4_t a1 = __builtin_amdgcn_mfma_f32_16x16x32_bf16(h0.v, bfr[0][1], z4, 0,0,0);
    f32x4_t a2 = __builtin_amdgcn_mfma_f32_16x16x32_bf16(h0.v, bfr[0][2], z4, 0,0,0);
    f32x4_t a3 = __builtin_amdgcn_mfma_f32_16x16x32_bf16(h0.v, bfr[0][3], z4, 0,0,0);
    a0 = __builtin_amdgcn_mfma_f32_16x16x32_bf16(h1.v, bfr[1][0], a0, 0,0,0);
    a1 = __builtin_amdgcn_mfma_f32_16x16x32_bf16(h1.v, bfr[1][1], a1, 0,0,0);
    a2 = __builtin_amdgcn_mfma_f32_16x16x32_bf16(h1.v, bfr[1][2], a2, 0,0,0);
    a3 = __builtin_amdgcn_mfma_f32_16x16x32_bf16(h1.v, bfr[1][3], a3, 0,0,0);
    *(f32x4_t*)(lds + (unsigned)(((w*4 + 0)*64 + l)*16)) = a0;
    *(f32x4_t*)(lds + (unsigned)(((w*4 + 1)*64 + l)*16)) = a1;
    *(f32x4_t*)(lds + (unsigned)(((w*4 + 2)*64 + l)*16)) = a2;
    *(f32x4_t*)(lds + (unsigned)(((w*4 + 3)*64 + l)*16)) = a3;
  }
  __syncthreads();
  float nn_out;
  {
    float v[16];
#pragma unroll
    for (int s = 0; s < 16; ++s)
      v[s] = *(const float*)(lds + (unsigned)(((s*4 + rnt)*64 + rq*16 + m)*16 + q*4));
    nn_out = (((v[0]+v[1]) + (v[2]+v[3])) + ((v[4]+v[5]) + (v[6]+v[7])))
           + (((v[8]+v[9]) + (v[10]+v[11])) + ((v[12]+v[13]) + (v[14]+v[15])));
    nn_out += nn_b2[rn];
  }
  __syncthreads();

  // ================= CNN conv + relu + pairwise maxpool -> pooled frags [0,51200) =====
  {
    const int cmm = tid & 15;
    const int ch  = (tid >> 4) & 31;
    const int hf  = tid >> 9;              // half of the 50 pooled positions
    const float cw0 = conv_w[ch*3+0], cw1 = conv_w[ch*3+1], cw2 = conv_w[ch*3+2];
    const float cbb = conv_b[ch];
    const float* xw = x + (row0 + cmm)*105 + 5;
    const int p0 = hf*25;
    float xm1  = (p0 == 0) ? 0.f : xw[2*p0 - 1];
    float xcur = xw[2*p0];
#pragma unroll 1
    for (int pp = 0; pp < 25; ++pp) {
      const int p = p0 + pp;
      const float xp1 = xw[2*p + 1];
      const float xp2 = (p < 49) ? xw[2*p + 2] : 0.f;
      float av = cw0*xm1  + cw1*xcur + cw2*xp1 + cbb;
      float bv = cw0*xcur + cw1*xp1  + cw2*xp2 + cbb;
      const float pv = fmaxf(fmaxf(av, 0.f), fmaxf(bv, 0.f));
      const int k = ch*50 + p;
      *(unsigned short*)(lds + (unsigned)((k>>5)*1024 + (((k>>3)&3)*16 + cmm)*16 + (k&7)*2)) = f2bfu(pv);
      xm1 = xp1; xcur = xp2;
    }
  }
  __syncthreads();

  // ================= CNN fc: wave w owns n-tile w (full K=1600) =================
  float fcout[4];
  {
    const int fn = w*16 + m;
    const float fbias = fc_b[fn];
    f32x4_t fe = z4, fo = z4;              // even/odd kc accumulators (ILP)
    if (use_bf) {
#pragma unroll 2
      for (int kc = 0; kc < 50; kc += 2) {
        const bf16x8_t ae = *(const bf16x8_t*)(lds + (unsigned)((kc*64 + l)*16));
        const bf16x8_t be = *(const bf16x8_t*)(fcwb + fn*1600 + kc*32 + q*8);
        fe = __builtin_amdgcn_mfma_f32_16x16x32_bf16(ae, be, fe, 0,0,0);
        const bf16x8_t ao = *(const bf16x8_t*)(lds + (unsigned)(((kc+1)*64 + l)*16));
        const bf16x8_t bo = *(const bf16x8_t*)(fcwb + fn*1600 + (kc+1)*32 + q*8);
        fo = __builtin_amdgcn_mfma_f32_16x16x32_bf16(ao, bo, fo, 0,0,0);
      }
    } else {
#pragma unroll 2
      for (int kc = 0; kc < 50; kc += 2) {
        const bf16x8_t ae = *(const bf16x8_t*)(lds + (unsigned)((kc*64 + l)*16));
        fe = __builtin_amdgcn_mfma_f32_16x16x32_bf16(ae, bfrag_f32(fc_w + fn*1600 + kc*32 + q*8, 1.f), fe, 0,0,0);
        const bf16x8_t ao = *(const bf16x8_t*)(lds + (unsigned)(((kc+1)*64 + l)*16));
        fo = __builtin_amdgcn_mfma_f32_16x16x32_bf16(ao, bfrag_f32(fc_w + fn*1600 + (kc+1)*32 + q*8, 1.f), fo, 0,0,0);
      }
    }
#pragma unroll
    for (int r = 0; r < 4; ++r) fcout[r] = (fe[r] + fo[r]) + fbias;
    // comb-input fragments (region [51200,63488) is dead: disjoint from pooled)
    comb_store(lds, rn,      rm, cnt * 0.0078125f);   // exact cnt/128
    comb_store(lds, 64 + rn, rm, nn_out);
#pragma unroll
    for (int r = 0; r < 4; ++r) comb_store(lds, 128 + fn, q*4 + r, fcout[r]);
  }
  __syncthreads();

  // ================= comb matmul: waves 0..11, one K-chunk each =================
  if (w < 12) {
    const float scale = (w < 2) ? 1.28f : 1.f;        // undo /128 on snn counts -> /100
    const bf16x8_t a = *(const bf16x8_t*)(lds + COMBF + (unsigned)((w*64 + l)*16));
#pragma unroll
    for (int nt = 0; nt < 4; ++nt) {
      const bf16x8_t b = bfrag_f32(comb_w + (nt*16 + m)*384 + w*32 + q*8, scale);
      const f32x4_t oc = __builtin_amdgcn_mfma_f32_16x16x32_bf16(a, b, z4, 0,0,0);
      *(f32x4_t*)(lds + (unsigned)(((w*4 + nt)*64 + l)*16)) = oc;   // pbuf2 at base 0
    }
  }
  __syncthreads();
  {
    float v[12];
#pragma unroll
    for (int s = 0; s < 12; ++s)
      v[s] = *(const float*)(lds + (unsigned)(((s*4 + rnt)*64 + rq*16 + m)*16 + q*4));
    float fin = (((v[0]+v[1]) + (v[2]+v[3])) + ((v[4]+v[5]) + (v[6]+v[7])))
              + ((v[8]+v[9]) + (v[10]+v[11]));
    out[(row0 + rm)*64 + rn] = fin + cbl;
  }
}

// fc_w fp32 -> bf16 (runs every call; d_ws is re-poisoned by the harness)
__global__ __launch_bounds__(256)
void fcw_to_bf16(const float* __restrict__ src, unsigned short* __restrict__ dst) {
  const int i = (blockIdx.x * 256 + threadIdx.x) * 4;
  const float4 v = *(const float4*)(src + i);
  ushort4 o;
  o.x = f2bfu(v.x); o.y = f2bfu(v.y); o.z = f2bfu(v.z); o.w = f2bfu(v.w);
  *(ushort4*)(dst + i) = o;
}

extern "C" void kernel_launch(void* const* d_in, const int* in_sizes, int n_in,
                              void* d_out, int out_size, void* d_ws, size_t ws_size,
                              hipStream_t stream) {
  const float* x       = (const float*)d_in[0];
  const float* snn_w1  = (const float*)d_in[1];
  const float* snn_b1  = (const float*)d_in[2];
  const float* snn_w2  = (const float*)d_in[3];
  const float* snn_b2  = (const float*)d_in[4];
  const float* nn_w1   = (const float*)d_in[5];
  const float* nn_b1   = (const float*)d_in[6];
  const float* nn_w2   = (const float*)d_in[7];
  const float* nn_b2   = (const float*)d_in[8];
  const float* conv_w  = (const float*)d_in[9];
  const float* conv_b  = (const float*)d_in[10];
  const float* fc_w    = (const float*)d_in[11];
  const float* fc_b    = (const float*)d_in[12];
  const float* comb_w  = (const float*)d_in[13];
  const float* comb_b  = (const float*)d_in[14];
  float* outp = (float*)d_out;

  const int rows = in_sizes[0] / 105;          // 16384
  const int grid = rows / 16;                  // 1024

  const size_t fcw_elems = (size_t)in_sizes[11];          // 256*1600 = 409600
  const int use_bf = (ws_size >= fcw_elems * 2) ? 1 : 0;
  unsigned short* fcwb = (unsigned short*)d_ws;
  if (use_bf) {
    fcw_to_bf16<<<dim3((unsigned)(fcw_elems / 1024)), dim3(256), 0, stream>>>(fc_w, fcwb);
  }

  hybrid_v2<<<dim3(grid), dim3(1024), 0, stream>>>(
      x, snn_w1, snn_b1, snn_w2, snn_b2,
      nn_w1, nn_b1, nn_w2, nn_b2,
      conv_w, conv_b, fc_w, fc_b, comb_w, comb_b,
      fcwb, use_bf, outp);
}

// Round 3
// 840.675 us; speedup vs baseline: 1.2304x; 1.1010x over previous
//
#include <hip/hip_runtime.h>

typedef __bf16 bf16x8_t __attribute__((ext_vector_type(8)));
typedef float f32x4_t __attribute__((ext_vector_type(4)));

#define NSTEPS 100
#define COMBF 51200u   // comb-input bf16 fragments at [51200, 63488)

static __device__ __forceinline__ unsigned short f2bfu(float v) {
  union { __bf16 h; unsigned short u; } c; c.h = (__bf16)v; return c.u;  // RTNE
}
static __device__ __forceinline__ unsigned int pack2bf(float a, float b) {
  return (unsigned)f2bfu(a) | ((unsigned)f2bfu(b) << 16);
}
union BF8U { unsigned int u[4]; bf16x8_t v; };

static __device__ __forceinline__ bf16x8_t bfrag_f32(const float* __restrict__ p, float s) {
  BF8U r;
#pragma unroll
  for (int i = 0; i < 4; ++i) r.u[i] = pack2bf(p[2*i]*s, p[2*i+1]*s);
  return r.v;
}

// store one bf16 element into the comb A-fragment region: k = feature, row = batch row
static __device__ __forceinline__ void comb_store(unsigned char* ldsp, int k, int row, float v) {
  *(unsigned short*)(ldsp + COMBF +
      (unsigned)((k >> 5)*1024 + (((k >> 3) & 3)*16 + row)*16 + (k & 7)*2)) = f2bfu(v);
}

// 512 threads = 8 waves = 2 waves/SIMD -> 256-VGPR budget: the 32-cell LIF state,
// 16 resident B-frags, afr and acc all fit with ~70 regs slack (no spill).
__global__ __launch_bounds__(512, 2)
void hybrid_v3(const float* __restrict__ x,
               const float* __restrict__ snn_w1, const float* __restrict__ snn_b1,
               const float* __restrict__ snn_w2, const float* __restrict__ snn_b2,
               const float* __restrict__ nn_w1,  const float* __restrict__ nn_b1,
               const float* __restrict__ nn_w2,  const float* __restrict__ nn_b2,
               const float* __restrict__ conv_w, const float* __restrict__ conv_b,
               const float* __restrict__ fc_w,   const float* __restrict__ fc_b,
               const float* __restrict__ comb_w, const float* __restrict__ comb_b,
               const unsigned short* __restrict__ fcwb, int use_bf,
               float* __restrict__ out)
{
  __shared__ __align__(16) unsigned char lds[65536];
  const int tid  = threadIdx.x;
  const int w    = tid >> 6;        // wave 0..7: owns K-chunks [4w, 4w+4)  (K slice of 128)
  const int l    = tid & 63;
  const int q    = l >> 4;
  const int m    = l & 15;
  const int row0 = blockIdx.x * 16;

  // reduction-cell ownership: lane owns cells (rA, rn) and (rB, rn)
  const int hi  = w >> 2;           // 0..1
  const int ntr = w & 3;            // n-tile of owned cells
  const int rn  = ntr*16 + m;       // 0..63
  const int rA  = hi*4 + q;         // 0..7
  const int rB  = rA + 8;           // 8..15

  const float* xr = x + (row0 + m)*105;
  const float f0 = xr[0], f1 = xr[1], f2 = xr[2], f3 = xr[3], f4 = xr[4];
  const float b2l = snn_b2[rn];

  // resident snn_w2 B-fragments: 4 k-chunks x 4 n-tiles (64 regs, AGPR-eligible)
  bf16x8_t bfr[4][4];
#pragma unroll
  for (int ci = 0; ci < 4; ++ci)
#pragma unroll
    for (int nt = 0; nt < 4; ++nt)
      bfr[ci][nt] = bfrag_f32(snn_w2 + (nt*16 + m)*1024 + (w*4 + ci)*32 + q*8, 1.f);

  // layer-1 LIF state: lane's 32 A-fragment cells (rows m, k = (4w+ci)*32 + q*8 + j)
  float c[32], mem[32];
  {
    const int kb = w*128 + q*8;
#pragma unroll
    for (int ci = 0; ci < 4; ++ci) {
      const float* wp = snn_w1 + (kb + ci*32)*5;      // 8 rows x 5 = 40 floats, 16B-aligned
      float wa[40];
#pragma unroll
      for (int u2 = 0; u2 < 10; ++u2) {
        const float4 t4 = *(const float4*)(wp + u2*4);
        wa[u2*4+0] = t4.x; wa[u2*4+1] = t4.y; wa[u2*4+2] = t4.z; wa[u2*4+3] = t4.w;
      }
#pragma unroll
      for (int j = 0; j < 8; ++j) {
        c[ci*8+j] = f0*wa[j*5] + f1*wa[j*5+1] + f2*wa[j*5+2] + f3*wa[j*5+3] + f4*wa[j*5+4]
                  + snn_b1[kb + ci*32 + j];
        mem[ci*8+j] = 0.f;
      }
    }
  }

  BF8U afr[4];
  auto lif_update_pack = [&]() {
#pragma unroll
    for (int i = 0; i < 32; ++i) {
      const float sp = mem[i] > 1.f ? 1.f : 0.f;               // spk == (mem>1) invariant
      mem[i] = __fsub_rn(__fadd_rn(__fmul_rn(0.95f, mem[i]), c[i]), sp);  // exact np order
    }
#pragma unroll
    for (int ci = 0; ci < 4; ++ci)
#pragma unroll
      for (int jj = 0; jj < 4; ++jj)
        afr[ci].u[jj] = (mem[ci*8 + 2*jj]   > 1.f ? 0x3F80u     : 0u)
                      | (mem[ci*8 + 2*jj+1] > 1.f ? 0x3F800000u : 0u);
  };
  lif_update_pack();                 // spikes(t=0) in registers

  // layer-2 LIF: two cells per lane
  float m2A = 0.f, s2A = 0.f, cntA = 0.f;
  float m2B = 0.f, s2B = 0.f, cntB = 0.f;

  const unsigned pbase = (unsigned)(ntr*1024 + hi*256 + m*16 + q*4);  // partial-read base
  const f32x4_t z4 = {0.f, 0.f, 0.f, 0.f};

#pragma unroll 1
  for (int t = 0; t < NSTEPS; ++t) {
    // PHASE A (short): MFMA on spikes(t), store K-partials
    f32x4_t acc[4] = {z4, z4, z4, z4};
#pragma unroll
    for (int ci = 0; ci < 4; ++ci) {
#pragma unroll
      for (int nt = 0; nt < 4; ++nt)
        acc[nt] = __builtin_amdgcn_mfma_f32_16x16x32_bf16(afr[ci].v, bfr[ci][nt], acc[nt], 0,0,0);
    }
#pragma unroll
    for (int nt = 0; nt < 4; ++nt)
      *(f32x4_t*)(lds + (unsigned)(((w*4 + nt)*64 + l)*16)) = acc[nt];
    __syncthreads();
    // PHASE B: issue partial reads; LIF(t+1) VALU overlaps the LDS drain (independent)
    float vA[8], vB[8];
#pragma unroll
    for (int s = 0; s < 8; ++s) vA[s] = *(const float*)(lds + pbase + (unsigned)(s*4096));
#pragma unroll
    for (int s = 0; s < 8; ++s) vB[s] = *(const float*)(lds + pbase + 512u + (unsigned)(s*4096));
    if (t < NSTEPS - 1) lif_update_pack();
    {
      float curA = (((vA[0]+vA[1]) + (vA[2]+vA[3])) + ((vA[4]+vA[5]) + (vA[6]+vA[7]))) + b2l;
      float curB = (((vB[0]+vB[1]) + (vB[2]+vB[3])) + ((vB[4]+vB[5]) + (vB[6]+vB[7]))) + b2l;
      m2A = __fsub_rn(__fadd_rn(__fmul_rn(0.95f, m2A), curA), s2A);
      s2A = m2A > 1.f ? 1.f : 0.f;  cntA += s2A;
      m2B = __fsub_rn(__fadd_rn(__fmul_rn(0.95f, m2B), curB), s2B);
      s2B = m2B > 1.f ? 1.f : 0.f;  cntB += s2B;
    }
    __syncthreads();
  }

  // ================= NN branch (same machinery, one shot) =================
#pragma unroll
  for (int ci = 0; ci < 4; ++ci)
#pragma unroll
    for (int nt = 0; nt < 4; ++nt)
      bfr[ci][nt] = bfrag_f32(nn_w2 + (nt*16 + m)*1024 + (w*4 + ci)*32 + q*8, 1.f);
  {
    BF8U hfr[4];
    const int kb = w*128 + q*8;
#pragma unroll
    for (int ci = 0; ci < 4; ++ci) {
      const float* wp = nn_w1 + (kb + ci*32)*5;
      float wa[40];
#pragma unroll
      for (int u2 = 0; u2 < 10; ++u2) {
        const float4 t4 = *(const float4*)(wp + u2*4);
        wa[u2*4+0] = t4.x; wa[u2*4+1] = t4.y; wa[u2*4+2] = t4.z; wa[u2*4+3] = t4.w;
      }
      float hv[8];
#pragma unroll
      for (int j = 0; j < 8; ++j) {
        const float h = f0*wa[j*5] + f1*wa[j*5+1] + f2*wa[j*5+2] + f3*wa[j*5+3] + f4*wa[j*5+4]
                      + nn_b1[kb + ci*32 + j];
        hv[j] = fmaxf(h, 0.f);
      }
#pragma unroll
      for (int jj = 0; jj < 4; ++jj) hfr[ci].u[jj] = pack2bf(hv[2*jj], hv[2*jj+1]);
    }
    f32x4_t acc[4] = {z4, z4, z4, z4};
#pragma unroll
    for (int ci = 0; ci < 4; ++ci)
#pragma unroll
      for (int nt = 0; nt < 4; ++nt)
        acc[nt] = __builtin_amdgcn_mfma_f32_16x16x32_bf16(hfr[ci].v, bfr[ci][nt], acc[nt], 0,0,0);
#pragma unroll
    for (int nt = 0; nt < 4; ++nt)
      *(f32x4_t*)(lds + (unsigned)(((w*4 + nt)*64 + l)*16)) = acc[nt];
  }
  __syncthreads();
  {
    float vA[8], vB[8];
#pragma unroll
    for (int s = 0; s < 8; ++s) vA[s] = *(const float*)(lds + pbase + (unsigned)(s*4096));
#pragma unroll
    for (int s = 0; s < 8; ++s) vB[s] = *(const float*)(lds + pbase + 512u + (unsigned)(s*4096));
    const float nA = (((vA[0]+vA[1]) + (vA[2]+vA[3])) + ((vA[4]+vA[5]) + (vA[6]+vA[7]))) + nn_b2[rn];
    const float nB = (((vB[0]+vB[1]) + (vB[2]+vB[3])) + ((vB[4]+vB[5]) + (vB[6]+vB[7]))) + nn_b2[rn];
    // comb inputs (region [51200,63488) is disjoint from partials/pooled)
    comb_store(lds, rn,      rA, cntA * 0.0078125f);   // exact cnt/128
    comb_store(lds, rn,      rB, cntB * 0.0078125f);
    comb_store(lds, 64 + rn, rA, nA);
    comb_store(lds, 64 + rn, rB, nB);
  }
  __syncthreads();   // partial reads done -> pooled region may overwrite [0,32K)

  // ======= CNN conv + relu + pairwise maxpool -> pooled bf16 frags [0,51200) =======
  {
    const int ch = tid >> 4;          // 0..31  (row = m)
    const float cw0 = conv_w[ch*3+0], cw1 = conv_w[ch*3+1], cw2 = conv_w[ch*3+2];
    const float cbb = conv_b[ch];
    const float* xw = xr + 5;
    float xm1 = 0.f, x0v = xw[0];
#pragma unroll 1
    for (int p = 0; p < 50; ++p) {
      const float xp1 = xw[2*p + 1];
      const float xp2 = (p < 49) ? xw[2*p + 2] : 0.f;
      const float av = cw0*xm1 + cw1*x0v + cw2*xp1 + cbb;
      const float bv = cw0*x0v + cw1*xp1 + cw2*xp2 + cbb;
      const float pv = fmaxf(fmaxf(av, 0.f), fmaxf(bv, 0.f));
      const int k = ch*50 + p;
      *(unsigned short*)(lds + (unsigned)((k>>5)*1024 + (((k>>3)&3)*16 + m)*16 + (k&7)*2)) = f2bfu(pv);
      xm1 = xp1; x0v = xp2;
    }
  }
  __syncthreads();

  // ================= CNN fc: wave w owns n-tiles {2w, 2w+1}, full K=1600 =================
  {
    const int c0 = (w*2 + 0)*16 + m;
    const int c1 = (w*2 + 1)*16 + m;
    f32x4_t e0 = z4, o0 = z4, e1 = z4, o1 = z4;
    if (use_bf) {
#pragma unroll 2
      for (int kc = 0; kc < 50; kc += 2) {
        const bf16x8_t a0 = *(const bf16x8_t*)(lds + (unsigned)((kc*64 + l)*16));
        const bf16x8_t a1 = *(const bf16x8_t*)(lds + (unsigned)(((kc+1)*64 + l)*16));
        e0 = __builtin_amdgcn_mfma_f32_16x16x32_bf16(a0, *(const bf16x8_t*)(fcwb + c0*1600 + kc*32 + q*8), e0, 0,0,0);
        o0 = __builtin_amdgcn_mfma_f32_16x16x32_bf16(a1, *(const bf16x8_t*)(fcwb + c0*1600 + (kc+1)*32 + q*8), o0, 0,0,0);
        e1 = __builtin_amdgcn_mfma_f32_16x16x32_bf16(a0, *(const bf16x8_t*)(fcwb + c1*1600 + kc*32 + q*8), e1, 0,0,0);
        o1 = __builtin_amdgcn_mfma_f32_16x16x32_bf16(a1, *(const bf16x8_t*)(fcwb + c1*1600 + (kc+1)*32 + q*8), o1, 0,0,0);
      }
    } else {
#pragma unroll 2
      for (int kc = 0; kc < 50; kc += 2) {
        const bf16x8_t a0 = *(const bf16x8_t*)(lds + (unsigned)((kc*64 + l)*16));
        const bf16x8_t a1 = *(const bf16x8_t*)(lds + (unsigned)(((kc+1)*64 + l)*16));
        e0 = __builtin_amdgcn_mfma_f32_16x16x32_bf16(a0, bfrag_f32(fc_w + c0*1600 + kc*32 + q*8, 1.f), e0, 0,0,0);
        o0 = __builtin_amdgcn_mfma_f32_16x16x32_bf16(a1, bfrag_f32(fc_w + c0*1600 + (kc+1)*32 + q*8, 1.f), o0, 0,0,0);
        e1 = __builtin_amdgcn_mfma_f32_16x16x32_bf16(a0, bfrag_f32(fc_w + c1*1600 + kc*32 + q*8, 1.f), e1, 0,0,0);
        o1 = __builtin_amdgcn_mfma_f32_16x16x32_bf16(a1, bfrag_f32(fc_w + c1*1600 + (kc+1)*32 + q*8, 1.f), o1, 0,0,0);
      }
    }
    const float fb0 = fc_b[c0], fb1 = fc_b[c1];
#pragma unroll
    for (int r = 0; r < 4; ++r) {
      comb_store(lds, 128 + c0, q*4 + r, (e0[r] + o0[r]) + fb0);
      comb_store(lds, 128 + c1, q*4 + r, (e1[r] + o1[r]) + fb1);
    }
  }
  __syncthreads();

  // ================= comb matmul: waves 0..3, wave nt = w owns full K=384 =================
  if (w < 4) {
    const int cn = w*16 + m;
    f32x4_t oe = z4, oo = z4;
#pragma unroll
    for (int kc = 0; kc < 12; kc += 2) {
      const bf16x8_t a0 = *(const bf16x8_t*)(lds + COMBF + (unsigned)((kc*64 + l)*16));
      const bf16x8_t a1 = *(const bf16x8_t*)(lds + COMBF + (unsigned)(((kc+1)*64 + l)*16));
      const float s0 = (kc    < 2) ? 1.28f : 1.f;   // undo /128 on snn counts -> /100
      const float s1 = (kc+1 < 2) ? 1.28f : 1.f;
      oe = __builtin_amdgcn_mfma_f32_16x16x32_bf16(a0, bfrag_f32(comb_w + cn*384 + kc*32 + q*8, s0), oe, 0,0,0);
      oo = __builtin_amdgcn_mfma_f32_16x16x32_bf16(a1, bfrag_f32(comb_w + cn*384 + (kc+1)*32 + q*8, s1), oo, 0,0,0);
    }
    const float cb2 = comb_b[cn];
#pragma unroll
    for (int r = 0; r < 4; ++r)
      out[(row0 + q*4 + r)*64 + cn] = (oe[r] + oo[r]) + cb2;
  }
}

// fc_w fp32 -> bf16 (runs every call; d_ws is re-poisoned by the harness)
__global__ __launch_bounds__(256)
void fcw_to_bf16(const float* __restrict__ src, unsigned short* __restrict__ dst) {
  const int i = (blockIdx.x * 256 + threadIdx.x) * 4;
  const float4 v = *(const float4*)(src + i);
  ushort4 o;
  o.x = f2bfu(v.x); o.y = f2bfu(v.y); o.z = f2bfu(v.z); o.w = f2bfu(v.w);
  *(ushort4*)(dst + i) = o;
}

extern "C" void kernel_launch(void* const* d_in, const int* in_sizes, int n_in,
                              void* d_out, int out_size, void* d_ws, size_t ws_size,
                              hipStream_t stream) {
  const float* x       = (const float*)d_in[0];
  const float* snn_w1  = (const float*)d_in[1];
  const float* snn_b1  = (const float*)d_in[2];
  const float* snn_w2  = (const float*)d_in[3];
  const float* snn_b2  = (const float*)d_in[4];
  const float* nn_w1   = (const float*)d_in[5];
  const float* nn_b1   = (const float*)d_in[6];
  const float* nn_w2   = (const float*)d_in[7];
  const float* nn_b2   = (const float*)d_in[8];
  const float* conv_w  = (const float*)d_in[9];
  const float* conv_b  = (const float*)d_in[10];
  const float* fc_w    = (const float*)d_in[11];
  const float* fc_b    = (const float*)d_in[12];
  const float* comb_w  = (const float*)d_in[13];
  const float* comb_b  = (const float*)d_in[14];
  float* outp = (float*)d_out;

  const int rows = in_sizes[0] / 105;          // 16384
  const int grid = rows / 16;                  // 1024

  const size_t fcw_elems = (size_t)in_sizes[11];          // 256*1600 = 409600
  const int use_bf = (ws_size >= fcw_elems * 2) ? 1 : 0;
  unsigned short* fcwb = (unsigned short*)d_ws;
  if (use_bf) {
    fcw_to_bf16<<<dim3((unsigned)(fcw_elems / 1024)), dim3(256), 0, stream>>>(fc_w, fcwb);
  }

  hybrid_v3<<<dim3(grid), dim3(512), 0, stream>>>(
      x, snn_w1, snn_b1, snn_w2, snn_b2,
      nn_w1, nn_b1, nn_w2, nn_b2,
      conv_w, conv_b, fc_w, fc_b, comb_w, comb_b,
      fcwb, use_bf, outp);
}

// Round 4
// 722.141 us; speedup vs baseline: 1.4323x; 1.1641x over previous
//
#include <hip/hip_runtime.h>

typedef __bf16 bf16x8_t __attribute__((ext_vector_type(8)));
typedef float f32x4_t __attribute__((ext_vector_type(4)));

#define NSTEPS 100
#define PB0 0u          // partials double-buffer: [0,32K) and [32K,64K)
#define PB1 32768u
#define COMBF 51200u    // comb-input bf16 fragments at [51200, 63488) (post-loop only)

static __device__ __forceinline__ unsigned short f2bfu(float v) {
  union { __bf16 h; unsigned short u; } c; c.h = (__bf16)v; return c.u;  // RTNE
}
static __device__ __forceinline__ unsigned int pack2bf(float a, float b) {
  return (unsigned)f2bfu(a) | ((unsigned)f2bfu(b) << 16);
}
union BF8U { unsigned int u[4]; bf16x8_t v; };

static __device__ __forceinline__ bf16x8_t bfrag_f32(const float* __restrict__ p, float s) {
  BF8U r;
#pragma unroll
  for (int i = 0; i < 4; ++i) r.u[i] = pack2bf(p[2*i]*s, p[2*i+1]*s);
  return r.v;
}

static __device__ __forceinline__ void comb_store(unsigned char* ldsp, int k, int row, float v) {
  *(unsigned short*)(ldsp + COMBF +
      (unsigned)((k >> 5)*1024 + (((k >> 3) & 3)*16 + row)*16 + (k & 7)*2)) = f2bfu(v);
}

// 512 threads = 8 waves = 2 waves/SIMD -> 256-reg unified budget; state fits, no spill.
__global__ __launch_bounds__(512, 2)
void hybrid_v4(const float* __restrict__ x,
               const float* __restrict__ snn_w1, const float* __restrict__ snn_b1,
               const float* __restrict__ snn_w2, const float* __restrict__ snn_b2,
               const float* __restrict__ nn_w1,  const float* __restrict__ nn_b1,
               const float* __restrict__ nn_w2,  const float* __restrict__ nn_b2,
               const float* __restrict__ conv_w, const float* __restrict__ conv_b,
               const float* __restrict__ fc_w,   const float* __restrict__ fc_b,
               const float* __restrict__ comb_w, const float* __restrict__ comb_b,
               const unsigned short* __restrict__ fcwb, int use_bf,
               float* __restrict__ out)
{
  __shared__ __align__(16) unsigned char lds[65536];
  const int tid  = threadIdx.x;
  const int w    = tid >> 6;        // wave 0..7: K-slice [128w, 128w+128)
  const int l    = tid & 63;
  const int q    = l >> 4;
  const int m    = l & 15;
  const int row0 = blockIdx.x * 16;

  const int hi  = w >> 2;
  const int ntr = w & 3;
  const int rn  = ntr*16 + m;       // owned output col 0..63
  const int rA  = hi*4 + q;         // owned row A 0..7
  const int rB  = rA + 8;           // owned row B 8..15

  const float* xr = x + (row0 + m)*105;
  const float f0 = xr[0], f1 = xr[1], f2 = xr[2], f3 = xr[3], f4 = xr[4];
  const float b2l = snn_b2[rn];

  // resident snn_w2 B-fragments: 4 k-chunks x 4 n-tiles (64 regs, AGPR-eligible)
  bf16x8_t bfr[4][4];
#pragma unroll
  for (int ci = 0; ci < 4; ++ci)
#pragma unroll
    for (int nt = 0; nt < 4; ++nt)
      bfr[ci][nt] = bfrag_f32(snn_w2 + (nt*16 + m)*1024 + (w*4 + ci)*32 + q*8, 1.f);

  // layer-1 LIF state: lane's 32 A-fragment cells
  float c[32], mem[32];
  {
    const int kb = w*128 + q*8;
#pragma unroll
    for (int ci = 0; ci < 4; ++ci) {
      const float* wp = snn_w1 + (kb + ci*32)*5;
      float wa[40];
#pragma unroll
      for (int u2 = 0; u2 < 10; ++u2) {
        const float4 t4 = *(const float4*)(wp + u2*4);
        wa[u2*4+0] = t4.x; wa[u2*4+1] = t4.y; wa[u2*4+2] = t4.z; wa[u2*4+3] = t4.w;
      }
#pragma unroll
      for (int j = 0; j < 8; ++j) {
        c[ci*8+j] = f0*wa[j*5] + f1*wa[j*5+1] + f2*wa[j*5+2] + f3*wa[j*5+3] + f4*wa[j*5+4]
                  + snn_b1[kb + ci*32 + j];
        mem[ci*8+j] = 0.f;
      }
    }
  }

  BF8U afr[4];
  auto lif_update_pack = [&]() {
#pragma unroll
    for (int i = 0; i < 32; ++i) {
      const float sp = mem[i] > 1.f ? 1.f : 0.f;               // spk == (mem>1) invariant
      mem[i] = __fsub_rn(__fadd_rn(__fmul_rn(0.95f, mem[i]), c[i]), sp);  // exact np order
    }
#pragma unroll
    for (int ci = 0; ci < 4; ++ci)
#pragma unroll
      for (int jj = 0; jj < 4; ++jj)
        afr[ci].u[jj] = (mem[ci*8 + 2*jj]   > 1.f ? 0x3F80u     : 0u)
                      | (mem[ci*8 + 2*jj+1] > 1.f ? 0x3F800000u : 0u);
  };
  lif_update_pack();                 // spikes(t=0) in registers

  float m2A = 0.f, s2A = 0.f, cntA = 0.f;
  float m2B = 0.f, s2B = 0.f, cntB = 0.f;

  const unsigned pbase  = (unsigned)(ntr*1024 + hi*256 + m*16 + q*4);   // reduce-read base
  const unsigned wtbase = (unsigned)((w*4*64 + l)*16);                   // partial-write base
  const f32x4_t z4 = {0.f, 0.f, 0.f, 0.f};

  // one phase of the software pipeline: reads(t-1) | MFMA(t)+writes | LIF(t+1) | reduce(t-1)
  auto phase = [&](unsigned cur, unsigned prv, bool doRead, bool doLif) {
    float vA[8], vB[8];
    if (doRead) {
#pragma unroll
      for (int s = 0; s < 8; ++s) vA[s] = *(const float*)(lds + prv + pbase + (unsigned)(s*4096));
#pragma unroll
      for (int s = 0; s < 8; ++s) vB[s] = *(const float*)(lds + prv + pbase + 512u + (unsigned)(s*4096));
    }
    f32x4_t acc[4] = {z4, z4, z4, z4};
#pragma unroll
    for (int ci = 0; ci < 4; ++ci)
#pragma unroll
      for (int nt = 0; nt < 4; ++nt)
        acc[nt] = __builtin_amdgcn_mfma_f32_16x16x32_bf16(afr[ci].v, bfr[ci][nt], acc[nt], 0,0,0);
#pragma unroll
    for (int nt = 0; nt < 4; ++nt)
      *(f32x4_t*)(lds + cur + wtbase + (unsigned)(nt*1024)) = acc[nt];
    if (doLif) lif_update_pack();
    if (doRead) {
      float curA = (((vA[0]+vA[1]) + (vA[2]+vA[3])) + ((vA[4]+vA[5]) + (vA[6]+vA[7]))) + b2l;
      float curB = (((vB[0]+vB[1]) + (vB[2]+vB[3])) + ((vB[4]+vB[5]) + (vB[6]+vB[7]))) + b2l;
      m2A = __fsub_rn(__fadd_rn(__fmul_rn(0.95f, m2A), curA), s2A);
      s2A = m2A > 1.f ? 1.f : 0.f;  cntA += s2A;
      m2B = __fsub_rn(__fadd_rn(__fmul_rn(0.95f, m2B), curB), s2B);
      s2B = m2B > 1.f ? 1.f : 0.f;  cntB += s2B;
    }
    __syncthreads();
  };

#pragma unroll 1
  for (int tt = 0; tt < NSTEPS; tt += 2) {
    phase(PB0, PB1, tt > 0, true);                 // t = tt   (even)
    phase(PB1, PB0, true,  tt + 1 < NSTEPS - 1);   // t = tt+1 (odd)
  }
  // partials(99) sit in PB1; reduced below, folded into the NN phase.

  // ============ NN branch + final SNN reduce (reads PB1, writes PB0) ============
#pragma unroll
  for (int ci = 0; ci < 4; ++ci)
#pragma unroll
    for (int nt = 0; nt < 4; ++nt)
      bfr[ci][nt] = bfrag_f32(nn_w2 + (nt*16 + m)*1024 + (w*4 + ci)*32 + q*8, 1.f);
  {
    // final SNN reduce (t = 99)
    float vA[8], vB[8];
#pragma unroll
    for (int s = 0; s < 8; ++s) vA[s] = *(const float*)(lds + PB1 + pbase + (unsigned)(s*4096));
#pragma unroll
    for (int s = 0; s < 8; ++s) vB[s] = *(const float*)(lds + PB1 + pbase + 512u + (unsigned)(s*4096));
    float curA = (((vA[0]+vA[1]) + (vA[2]+vA[3])) + ((vA[4]+vA[5]) + (vA[6]+vA[7]))) + b2l;
    float curB = (((vB[0]+vB[1]) + (vB[2]+vB[3])) + ((vB[4]+vB[5]) + (vB[6]+vB[7]))) + b2l;
    m2A = __fsub_rn(__fadd_rn(__fmul_rn(0.95f, m2A), curA), s2A);
    s2A = m2A > 1.f ? 1.f : 0.f;  cntA += s2A;
    m2B = __fsub_rn(__fadd_rn(__fmul_rn(0.95f, m2B), curB), s2B);
    s2B = m2B > 1.f ? 1.f : 0.f;  cntB += s2B;

    // NN hidden + MFMA
    BF8U hfr[4];
    const int kb = w*128 + q*8;
#pragma unroll
    for (int ci = 0; ci < 4; ++ci) {
      const float* wp = nn_w1 + (kb + ci*32)*5;
      float wa[40];
#pragma unroll
      for (int u2 = 0; u2 < 10; ++u2) {
        const float4 t4 = *(const float4*)(wp + u2*4);
        wa[u2*4+0] = t4.x; wa[u2*4+1] = t4.y; wa[u2*4+2] = t4.z; wa[u2*4+3] = t4.w;
      }
      float hv[8];
#pragma unroll
      for (int j = 0; j < 8; ++j) {
        const float h = f0*wa[j*5] + f1*wa[j*5+1] + f2*wa[j*5+2] + f3*wa[j*5+3] + f4*wa[j*5+4]
                      + nn_b1[kb + ci*32 + j];
        hv[j] = fmaxf(h, 0.f);
      }
#pragma unroll
      for (int jj = 0; jj < 4; ++jj) hfr[ci].u[jj] = pack2bf(hv[2*jj], hv[2*jj+1]);
    }
    f32x4_t acc[4] = {z4, z4, z4, z4};
#pragma unroll
    for (int ci = 0; ci < 4; ++ci)
#pragma unroll
      for (int nt = 0; nt < 4; ++nt)
        acc[nt] = __builtin_amdgcn_mfma_f32_16x16x32_bf16(hfr[ci].v, bfr[ci][nt], acc[nt], 0,0,0);
#pragma unroll
    for (int nt = 0; nt < 4; ++nt)
      *(f32x4_t*)(lds + PB0 + wtbase + (unsigned)(nt*1024)) = acc[nt];
  }
  __syncthreads();
  {
    float vA[8], vB[8];
#pragma unroll
    for (int s = 0; s < 8; ++s) vA[s] = *(const float*)(lds + PB0 + pbase + (unsigned)(s*4096));
#pragma unroll
    for (int s = 0; s < 8; ++s) vB[s] = *(const float*)(lds + PB0 + pbase + 512u + (unsigned)(s*4096));
    const float nA = (((vA[0]+vA[1]) + (vA[2]+vA[3])) + ((vA[4]+vA[5]) + (vA[6]+vA[7]))) + nn_b2[rn];
    const float nB = (((vB[0]+vB[1]) + (vB[2]+vB[3])) + ((vB[4]+vB[5]) + (vB[6]+vB[7]))) + nn_b2[rn];
    comb_store(lds, rn,      rA, cntA * 0.0078125f);   // exact cnt/128
    comb_store(lds, rn,      rB, cntB * 0.0078125f);
    comb_store(lds, 64 + rn, rA, nA);
    comb_store(lds, 64 + rn, rB, nB);
  }
  __syncthreads();

  // ======= CNN conv + relu + pairwise maxpool -> pooled bf16 frags [0,51200) =======
  {
    const int ch = tid >> 4;          // 0..31  (row = m)
    const float cw0 = conv_w[ch*3+0], cw1 = conv_w[ch*3+1], cw2 = conv_w[ch*3+2];
    const float cbb = conv_b[ch];
    const float* xw = xr + 5;
    float xm1 = 0.f, x0v = xw[0];
#pragma unroll 1
    for (int p = 0; p < 50; ++p) {
      const float xp1 = xw[2*p + 1];
      const float xp2 = (p < 49) ? xw[2*p + 2] : 0.f;
      const float av = cw0*xm1 + cw1*x0v + cw2*xp1 + cbb;
      const float bv = cw0*x0v + cw1*xp1 + cw2*xp2 + cbb;
      const float pv = fmaxf(fmaxf(av, 0.f), fmaxf(bv, 0.f));
      const int k = ch*50 + p;
      *(unsigned short*)(lds + (unsigned)((k>>5)*1024 + (((k>>3)&3)*16 + m)*16 + (k&7)*2)) = f2bfu(pv);
      xm1 = xp1; x0v = xp2;
    }
  }
  __syncthreads();

  // ================= CNN fc: wave w owns n-tiles {2w, 2w+1}, full K=1600 =================
  {
    const int c0 = (w*2 + 0)*16 + m;
    const int c1 = (w*2 + 1)*16 + m;
    f32x4_t e0 = z4, o0 = z4, e1 = z4, o1 = z4;
    if (use_bf) {
#pragma unroll 2
      for (int kc = 0; kc < 50; kc += 2) {
        const bf16x8_t a0 = *(const bf16x8_t*)(lds + (unsigned)((kc*64 + l)*16));
        const bf16x8_t a1 = *(const bf16x8_t*)(lds + (unsigned)(((kc+1)*64 + l)*16));
        e0 = __builtin_amdgcn_mfma_f32_16x16x32_bf16(a0, *(const bf16x8_t*)(fcwb + c0*1600 + kc*32 + q*8), e0, 0,0,0);
        o0 = __builtin_amdgcn_mfma_f32_16x16x32_bf16(a1, *(const bf16x8_t*)(fcwb + c0*1600 + (kc+1)*32 + q*8), o0, 0,0,0);
        e1 = __builtin_amdgcn_mfma_f32_16x16x32_bf16(a0, *(const bf16x8_t*)(fcwb + c1*1600 + kc*32 + q*8), e1, 0,0,0);
        o1 = __builtin_amdgcn_mfma_f32_16x16x32_bf16(a1, *(const bf16x8_t*)(fcwb + c1*1600 + (kc+1)*32 + q*8), o1, 0,0,0);
      }
    } else {
#pragma unroll 2
      for (int kc = 0; kc < 50; kc += 2) {
        const bf16x8_t a0 = *(const bf16x8_t*)(lds + (unsigned)((kc*64 + l)*16));
        const bf16x8_t a1 = *(const bf16x8_t*)(lds + (unsigned)(((kc+1)*64 + l)*16));
        e0 = __builtin_amdgcn_mfma_f32_16x16x32_bf16(a0, bfrag_f32(fc_w + c0*1600 + kc*32 + q*8, 1.f), e0, 0,0,0);
        o0 = __builtin_amdgcn_mfma_f32_16x16x32_bf16(a1, bfrag_f32(fc_w + c0*1600 + (kc+1)*32 + q*8, 1.f), o0, 0,0,0);
        e1 = __builtin_amdgcn_mfma_f32_16x16x32_bf16(a0, bfrag_f32(fc_w + c1*1600 + kc*32 + q*8, 1.f), e1, 0,0,0);
        o1 = __builtin_amdgcn_mfma_f32_16x16x32_bf16(a1, bfrag_f32(fc_w + c1*1600 + (kc+1)*32 + q*8, 1.f), o1, 0,0,0);
      }
    }
    const float fb0 = fc_b[c0], fb1 = fc_b[c1];
#pragma unroll
    for (int r = 0; r < 4; ++r) {
      comb_store(lds, 128 + c0, q*4 + r, (e0[r] + o0[r]) + fb0);
      comb_store(lds, 128 + c1, q*4 + r, (e1[r] + o1[r]) + fb1);
    }
  }
  __syncthreads();

  // ================= comb matmul: waves 0..3, wave w owns n-tile w, full K=384 =================
  if (w < 4) {
    const int cn = w*16 + m;
    f32x4_t oe = z4, oo = z4;
#pragma unroll
    for (int kc = 0; kc < 12; kc += 2) {
      const bf16x8_t a0 = *(const bf16x8_t*)(lds + COMBF + (unsigned)((kc*64 + l)*16));
      const bf16x8_t a1 = *(const bf16x8_t*)(lds + COMBF + (unsigned)(((kc+1)*64 + l)*16));
      const float s0 = (kc    < 2) ? 1.28f : 1.f;   // undo /128 on snn counts -> /100
      const float s1 = (kc+1 < 2) ? 1.28f : 1.f;
      oe = __builtin_amdgcn_mfma_f32_16x16x32_bf16(a0, bfrag_f32(comb_w + cn*384 + kc*32 + q*8, s0), oe, 0,0,0);
      oo = __builtin_amdgcn_mfma_f32_16x16x32_bf16(a1, bfrag_f32(comb_w + cn*384 + (kc+1)*32 + q*8, s1), oo, 0,0,0);
    }
    const float cb2 = comb_b[cn];
#pragma unroll
    for (int r = 0; r < 4; ++r)
      out[(row0 + q*4 + r)*64 + cn] = (oe[r] + oo[r]) + cb2;
  }
}

// fc_w fp32 -> bf16 (runs every call; d_ws is re-poisoned by the harness)
__global__ __launch_bounds__(256)
void fcw_to_bf16(const float* __restrict__ src, unsigned short* __restrict__ dst) {
  const int i = (blockIdx.x * 256 + threadIdx.x) * 4;
  const float4 v = *(const float4*)(src + i);
  ushort4 o;
  o.x = f2bfu(v.x); o.y = f2bfu(v.y); o.z = f2bfu(v.z); o.w = f2bfu(v.w);
  *(ushort4*)(dst + i) = o;
}

extern "C" void kernel_launch(void* const* d_in, const int* in_sizes, int n_in,
                              void* d_out, int out_size, void* d_ws, size_t ws_size,
                              hipStream_t stream) {
  const float* x       = (const float*)d_in[0];
  const float* snn_w1  = (const float*)d_in[1];
  const float* snn_b1  = (const float*)d_in[2];
  const float* snn_w2  = (const float*)d_in[3];
  const float* snn_b2  = (const float*)d_in[4];
  const float* nn_w1   = (const float*)d_in[5];
  const float* nn_b1   = (const float*)d_in[6];
  const float* nn_w2   = (const float*)d_in[7];
  const float* nn_b2   = (const float*)d_in[8];
  const float* conv_w  = (const float*)d_in[9];
  const float* conv_b  = (const float*)d_in[10];
  const float* fc_w    = (const float*)d_in[11];
  const float* fc_b    = (const float*)d_in[12];
  const float* comb_w  = (const float*)d_in[13];
  const float* comb_b  = (const float*)d_in[14];
  float* outp = (float*)d_out;

  const int rows = in_sizes[0] / 105;          // 16384
  const int grid = rows / 16;                  // 1024

  const size_t fcw_elems = (size_t)in_sizes[11];          // 256*1600 = 409600
  const int use_bf = (ws_size >= fcw_elems * 2) ? 1 : 0;
  unsigned short* fcwb = (unsigned short*)d_ws;
  if (use_bf) {
    fcw_to_bf16<<<dim3((unsigned)(fcw_elems / 1024)), dim3(256), 0, stream>>>(fc_w, fcwb);
  }

  hybrid_v4<<<dim3(grid), dim3(512), 0, stream>>>(
      x, snn_w1, snn_b1, snn_w2, snn_b2,
      nn_w1, nn_b1, nn_w2, nn_b2,
      conv_w, conv_b, fc_w, fc_b, comb_w, comb_b,
      fcwb, use_bf, outp);
}